// Round 4
// baseline (521.938 us; speedup 1.0000x reference)
//
#include <hip/hip_runtime.h>
#include <hip/hip_bf16.h>
#include <math.h>

// Problem constants (B=2, C=256, H=W=64, heads=8, hd=32, groups=32, hid=64)
#define NB 2
#define NC 256
#define NHEAD 8
#define HD 32
#define NPIX 4096
#define GEPS 1e-5f

typedef short bf16x8 __attribute__((ext_vector_type(8)));
typedef float f32x4 __attribute__((ext_vector_type(4)));

union U16x8 { uint4 u4; uint2 u2[2]; unsigned u32[4]; unsigned short us[8]; bf16x8 v; };

__device__ inline unsigned short tobf(float f) {  // round-to-nearest-even
  union { float f; unsigned u; } c; c.f = f;
  return (unsigned short)((c.u + 0x7FFFu + ((c.u >> 16) & 1u)) >> 16);
}
__device__ inline unsigned packtrunc(float lo, float hi) {  // truncating bf16 pack
  return (__float_as_uint(lo) >> 16) | (__float_as_uint(hi) & 0xFFFF0000u);
}

// ---------------------------------------------------------------------------
// Dtype detection (bf16 vs fp32 inputs).
// ---------------------------------------------------------------------------
__global__ void detect_kernel(const void* __restrict__ x, int* __restrict__ flag) {
  int lane = threadIdx.x;
  const unsigned short* u = (const unsigned short*)x;
  unsigned short h = u[2 * lane];
  unsigned e = (h >> 7) & 0xFFu;
  int weird = (e < 113u || e > 140u) ? 1 : 0;
  unsigned long long mask = __ballot(weird);
  if (lane == 0) flag[0] = (__popcll(mask) > 16) ? 0 : 1;
}

struct ConvArgs { const void* src[13]; int off[14]; };

__global__ __launch_bounds__(256) void convert_all_kernel(ConvArgs a, float* __restrict__ dstbase,
                                                          const int* __restrict__ flag, int total) {
  int i = blockIdx.x * 256 + threadIdx.x;
  if (i >= total) return;
  int s = 0;
  while (i >= a.off[s + 1]) ++s;
  int local = i - a.off[s];
  if (*flag) {
    unsigned v = ((const unsigned short*)a.src[s])[local];
    dstbase[i] = __uint_as_float(v << 16);
  } else {
    dstbase[i] = ((const float*)a.src[s])[local];
  }
}

// ---------------------------------------------------------------------------
// Prep: weights fp32->bf16 (row-major [o][k], MFMA A-side) + Q scale vector
// qscale[o] = clip(temp[head])*log2(e) for o<256 else 1.
// ---------------------------------------------------------------------------
__global__ __launch_bounds__(256) void prep_kernel(
    const float* __restrict__ wqkv, const float* __restrict__ wout,
    const float* __restrict__ wm1, const float* __restrict__ wm2,
    const float* __restrict__ temp,
    unsigned short* __restrict__ wqkv_b, unsigned short* __restrict__ wout_b,
    unsigned short* __restrict__ wm1_b, unsigned short* __restrict__ wm2_b,
    float* __restrict__ qscale) {
  int i = blockIdx.x * 256 + threadIdx.x;
  if (i < 196608) wqkv_b[i] = tobf(wqkv[i]);
  else if (i < 262144) wout_b[i - 196608] = tobf(wout[i - 196608]);
  else if (i < 278528) wm1_b[i - 262144] = tobf(wm1[i - 262144]);
  else if (i < 294912) wm2_b[i - 278528] = tobf(wm2[i - 278528]);
  if (i < 768) {
    if (i < 256) {
      float tc = fminf(fmaxf(temp[i >> 5], 1e-4f), 10.f);
      qscale[i] = tc * 1.4426950408889634f;
    } else qscale[i] = 1.0f;
  }
}

// ---------------------------------------------------------------------------
// GroupNorm -> transposed bf16 output [p][256] (pixel-major for MFMA B-frags).
// One block per (b, group); group slab contiguous in fp32 [c][n] input.
// ---------------------------------------------------------------------------
__global__ __launch_bounds__(256) void gn_t_kernel(const float* __restrict__ in,
                                                   const float* __restrict__ gamma,
                                                   const float* __restrict__ beta,
                                                   unsigned short* __restrict__ outt) {
  int bg = blockIdx.x;
  int b = bg >> 5, g = bg & 31;
  const float* base = in + ((size_t)b * NC + g * 8) * NPIX;
  int t = threadIdx.x;
  float s = 0.f, s2 = 0.f;
  for (int i = t; i < 8 * NPIX; i += 256) {
    float v = base[i]; s += v; s2 += v * v;
  }
  __shared__ float rs[256], rq[256];
  rs[t] = s; rq[t] = s2;
  __syncthreads();
  for (int o = 128; o > 0; o >>= 1) {
    if (t < o) { rs[t] += rs[t + o]; rq[t] += rq[t + o]; }
    __syncthreads();
  }
  __shared__ float mean_s, inv_s;
  if (t == 0) {
    float mean = rs[0] * (1.f / 32768.f);
    float var = rq[0] * (1.f / 32768.f) - mean * mean;
    mean_s = mean; inv_s = rsqrtf(var + GEPS);
  }
  __syncthreads();
  float mean = mean_s, inv = inv_s;
  float gam[8], bet[8];
#pragma unroll
  for (int cc = 0; cc < 8; ++cc) {
    float gg = gamma[g * 8 + cc] * inv;
    gam[cc] = gg;
    bet[cc] = beta[g * 8 + cc] - mean * gg;
  }
  for (int n = t; n < NPIX; n += 256) {
    U16x8 pk;
#pragma unroll
    for (int cc = 0; cc < 8; ++cc)
      pk.us[cc] = tobf(base[cc * NPIX + n] * gam[cc] + bet[cc]);
    *(uint4*)(outt + ((size_t)(b * NPIX + n)) * NC + g * 8) = pk.u4;
  }
}

// ---------------------------------------------------------------------------
// bf16 MFMA GEMM, LDS-free: W [M][K] bf16 row-major (A), X [p][K] bf16
// pixel-major (B). Wave: OT o-tiles x 16 pixels; block: 4 waves splitting o.
// EPI 0: bf16 pixel-major out (scale/bias/ACT optional, OSTR row stride)
// EPI 1: fp32 channel-major out + bias + residual
// EPI 2: final out (flag dtype) + bias + residual, channel-major
// ---------------------------------------------------------------------------
template <int K, int OT, int EPI, int ACT, int OSTR>
__global__ __launch_bounds__(256) void mfma_gemm(
    const unsigned short* __restrict__ W, const unsigned short* __restrict__ X,
    const float* __restrict__ scale, const float* __restrict__ bias,
    const float* __restrict__ res, void* __restrict__ out,
    const int* __restrict__ flag) {
  int t = threadIdx.x;
  int w = t >> 6, lane = t & 63, l16 = lane & 15, quad = lane >> 4;
  int p = blockIdx.x * 16 + l16;
  int ob = blockIdx.y * (64 * OT) + w * (16 * OT);
  const unsigned short* xrow = X + (size_t)p * K + quad * 8;
  f32x4 acc[OT] = {};
#pragma unroll
  for (int k0 = 0; k0 < K; k0 += 32) {
    U16x8 bfr; bfr.u4 = *(const uint4*)(xrow + k0);
#pragma unroll
    for (int ot = 0; ot < OT; ++ot) {
      U16x8 af;
      af.u4 = *(const uint4*)(W + (size_t)(ob + ot * 16 + l16) * K + k0 + quad * 8);
      acc[ot] = __builtin_amdgcn_mfma_f32_16x16x32_bf16(af.v, bfr.v, acc[ot], 0, 0, 0);
    }
  }
  int b = p >> 12, n = p & 4095;
  int wbf = (EPI == 2) ? *flag : 0;
#pragma unroll
  for (int ot = 0; ot < OT; ++ot) {
    int oc = ob + ot * 16 + quad * 4;
    float v[4];
#pragma unroll
    for (int r = 0; r < 4; ++r) {
      float vv = acc[ot][r];
      if (scale) vv *= scale[oc + r];
      if (bias) vv += bias[oc + r];
      if (ACT == 1) vv = 0.5f * vv * (1.f + erff(vv * 0.70710678118654752f));
      v[r] = vv;
    }
    if (EPI == 0) {
      uint2 pk;
      pk.x = (unsigned)tobf(v[0]) | ((unsigned)tobf(v[1]) << 16);
      pk.y = (unsigned)tobf(v[2]) | ((unsigned)tobf(v[3]) << 16);
      *(uint2*)((unsigned short*)out + (size_t)p * OSTR + oc) = pk;
    } else {
#pragma unroll
      for (int r = 0; r < 4; ++r) {
        size_t oidx = ((size_t)(b * NC + oc + r)) * NPIX + n;
        float vv = v[r] + res[oidx];
        if (EPI == 2) {
          if (wbf) ((__hip_bfloat16*)out)[oidx] = __float2bfloat16(vv);
          else ((float*)out)[oidx] = vv;
        } else {
          ((float*)out)[oidx] = vv;
        }
      }
    }
  }
}

// ---------------------------------------------------------------------------
// V repack: qkv_t[p][512+c] (pixel-major) -> vs[b][c][n] (channel-major) via
// LDS 64x64 tile transpose.
// ---------------------------------------------------------------------------
__global__ __launch_bounds__(256) void vrepack_kernel(const unsigned short* __restrict__ qkvt,
                                                      unsigned short* __restrict__ vs) {
  __shared__ unsigned short ld[64][68];
  int t = threadIdx.x;
  int p0 = blockIdx.x * 64, c0 = blockIdx.y * 64;
  int b = p0 >> 12, n0 = p0 & 4095;
#pragma unroll
  for (int half = 0; half < 2; ++half) {
    int r = (t >> 3) + half * 32;
    int cc = (t & 7) * 8;
    *(uint4*)&ld[r][cc] = *(const uint4*)(qkvt + (size_t)(p0 + r) * 768 + 512 + c0 + cc);
  }
  __syncthreads();
  int cr = t >> 2, pc = (t & 3) * 16;
  U16x8 a, bq;
#pragma unroll
  for (int q = 0; q < 8; ++q) a.us[q] = ld[pc + q][cr];
#pragma unroll
  for (int q = 0; q < 8; ++q) bq.us[q] = ld[pc + 8 + q][cr];
  unsigned short* dst = vs + ((size_t)(b * NC) + c0 + cr) * NPIX + n0 + pc;
  *(uint4*)dst = a.u4;
  *(uint4*)(dst + 8) = bq.u4;
}

// ---------------------------------------------------------------------------
// MFMA flash attention v2. S^T = K^T Q (Q pre-scaled by temp*log2e in QKV
// GEMM); P = exp2(S^T) truncated to bf16; O^T = V P^T; l via ones-MFMA on
// the same truncated P (bias cancels). K/V frags prefetched one j-tile ahead
// (branchless wraparound). Outputs packed bf16 pixel-major [p][256].
// ---------------------------------------------------------------------------
__global__ __launch_bounds__(256) void attn2_kernel(const unsigned short* __restrict__ qkvt,
                                                    const unsigned short* __restrict__ vs,
                                                    unsigned short* __restrict__ aout_t) {
  int i0 = blockIdx.x * 64;
  int h = blockIdx.y, b = blockIdx.z;
  int t = threadIdx.x;
  int w = t >> 6, lane = t & 63, l16 = lane & 15, quad = lane >> 4;

  __shared__ unsigned short Pl[4][16][72];

  const size_t pbase = (size_t)b * NPIX;
  int pi = i0 + w * 16 + l16;

  U16x8 qf; qf.u4 = *(const uint4*)(qkvt + (pbase + pi) * 768 + h * 32 + quad * 8);
  U16x8 ones;
#pragma unroll
  for (int j = 0; j < 8; ++j) ones.us[j] = 0x3F80;

  const unsigned short* kcol = qkvt + pbase * 768 + 256 + h * 32 + quad * 8;  // + j*768
  const unsigned short* vrow0 = vs + ((size_t)(b * NC) + h * 32 + l16) * NPIX + quad * 8;
  const unsigned short* vrow1 = vrow0 + (size_t)16 * NPIX;

  f32x4 o0 = {0.f, 0.f, 0.f, 0.f}, o1 = {0.f, 0.f, 0.f, 0.f};
  f32x4 lacc = {0.f, 0.f, 0.f, 0.f};
  const f32x4 zf = {0.f, 0.f, 0.f, 0.f};

  U16x8 kf[4], vf0[2], vf1[2];
#pragma unroll
  for (int jt = 0; jt < 4; ++jt)
    kf[jt].u4 = *(const uint4*)(kcol + (size_t)(jt * 16 + l16) * 768);
#pragma unroll
  for (int ks = 0; ks < 2; ++ks) {
    vf0[ks].u4 = *(const uint4*)(vrow0 + ks * 32);
    vf1[ks].u4 = *(const uint4*)(vrow1 + ks * 32);
  }

  for (int j0 = 0; j0 < NPIX; j0 += 64) {
    int jn = (j0 + 64) & (NPIX - 1);  // wraps on last iter; harmless prefetch
    U16x8 kn[4], vn0[2], vn1[2];
#pragma unroll
    for (int jt = 0; jt < 4; ++jt)
      kn[jt].u4 = *(const uint4*)(kcol + (size_t)(jn + jt * 16 + l16) * 768);
#pragma unroll
    for (int ks = 0; ks < 2; ++ks) {
      vn0[ks].u4 = *(const uint4*)(vrow0 + jn + ks * 32);
      vn1[ks].u4 = *(const uint4*)(vrow1 + jn + ks * 32);
    }
    f32x4 st[4];
#pragma unroll
    for (int jt = 0; jt < 4; ++jt)
      st[jt] = __builtin_amdgcn_mfma_f32_16x16x32_bf16(kf[jt].v, qf.v, zf, 0, 0, 0);
#pragma unroll
    for (int jt = 0; jt < 4; ++jt) {
      uint2 pk;
      pk.x = packtrunc(__builtin_amdgcn_exp2f(st[jt][0]), __builtin_amdgcn_exp2f(st[jt][1]));
      pk.y = packtrunc(__builtin_amdgcn_exp2f(st[jt][2]), __builtin_amdgcn_exp2f(st[jt][3]));
      *(uint2*)&Pl[w][l16][jt * 16 + quad * 4] = pk;
    }
#pragma unroll
    for (int ks = 0; ks < 2; ++ks) {
      U16x8 pb; pb.u4 = *(const uint4*)&Pl[w][l16][ks * 32 + quad * 8];
      o0 = __builtin_amdgcn_mfma_f32_16x16x32_bf16(vf0[ks].v, pb.v, o0, 0, 0, 0);
      o1 = __builtin_amdgcn_mfma_f32_16x16x32_bf16(vf1[ks].v, pb.v, o1, 0, 0, 0);
      lacc = __builtin_amdgcn_mfma_f32_16x16x32_bf16(ones.v, pb.v, lacc, 0, 0, 0);
    }
#pragma unroll
    for (int jt = 0; jt < 4; ++jt) kf[jt] = kn[jt];
#pragma unroll
    for (int ks = 0; ks < 2; ++ks) { vf0[ks] = vn0[ks]; vf1[ks] = vn1[ks]; }
  }

  float rinv = 1.0f / lacc[0];  // all 4 regs hold l[col=l16]
  uint2 s0, s1;
  s0.x = (unsigned)tobf(o0[0] * rinv) | ((unsigned)tobf(o0[1] * rinv) << 16);
  s0.y = (unsigned)tobf(o0[2] * rinv) | ((unsigned)tobf(o0[3] * rinv) << 16);
  s1.x = (unsigned)tobf(o1[0] * rinv) | ((unsigned)tobf(o1[1] * rinv) << 16);
  s1.y = (unsigned)tobf(o1[2] * rinv) | ((unsigned)tobf(o1[3] * rinv) << 16);
  unsigned short* obp = aout_t + (pbase + pi) * NC + h * 32 + quad * 4;
  *(uint2*)obp = s0;
  *(uint2*)(obp + 16) = s1;
}

// ---------------------------------------------------------------------------
// Launch pipeline. NOTE: off is in FLOAT units; a bf16 buffer of N elements
// must advance off by N/2 (this was the round-3 bug: N/4 → buffer overlap).
// ---------------------------------------------------------------------------
extern "C" void kernel_launch(void* const* d_in, const int* in_sizes, int n_in,
                              void* d_out, int out_size, void* d_ws, size_t ws_size,
                              hipStream_t stream) {
  float* ws = (float*)d_ws;
  int* flag = (int*)d_ws;
  size_t off = 16;
  // fp32 master copies of the 13 inputs (contiguous, convert_all order):
  float* x_f    = ws + off; off += (size_t)NB * NC * NPIX;
  float* wqkv_f = ws + off; off += 768 * 256;
  float* wout_f = ws + off; off += 256 * 256;
  float* bout_f = ws + off; off += 256;
  float* temp_f = ws + off; off += 8;
  float* g1_f   = ws + off; off += 256;
  float* be1_f  = ws + off; off += 256;
  float* g2_f   = ws + off; off += 256;
  float* be2_f  = ws + off; off += 256;
  float* wm1_f  = ws + off; off += 64 * 256;
  float* bm1_f  = ws + off; off += 64;
  float* wm2_f  = ws + off; off += 256 * 64;
  float* bm2_f  = ws + off; off += 256;
  float* xres   = ws + off; off += (size_t)NB * NC * NPIX;
  unsigned short* xn_t   = (unsigned short*)(ws + off); off += 1048576;  // [8192][256] bf16
  unsigned short* qkv_t  = (unsigned short*)(ws + off); off += 3145728;  // [8192][768] bf16
  unsigned short* vs     = (unsigned short*)(ws + off); off += 1048576;  // [2][256][4096] bf16
  unsigned short* aout_t = (unsigned short*)(ws + off); off += 1048576;  // [8192][256] bf16
  unsigned short* ybuf_t = (unsigned short*)(ws + off); off += 1048576;  // [8192][256] bf16
  unsigned short* h_t    = (unsigned short*)(ws + off); off += 262144;   // [8192][64] bf16
  unsigned short* wqkv_b = (unsigned short*)(ws + off); off += 98304;
  unsigned short* wout_b = (unsigned short*)(ws + off); off += 32768;
  unsigned short* wm1_b  = (unsigned short*)(ws + off); off += 8192;
  unsigned short* wm2_b  = (unsigned short*)(ws + off); off += 8192;
  float* qscale = ws + off; off += 768;

  detect_kernel<<<1, 64, 0, stream>>>(d_in[0], flag);

  ConvArgs ca;
  int acc = 0;
  for (int i = 0; i < 13; ++i) {
    ca.src[i] = d_in[i];
    ca.off[i] = acc;
    acc += (i < n_in) ? in_sizes[i] : 0;
  }
  ca.off[13] = acc;
  convert_all_kernel<<<(acc + 255) / 256, 256, 0, stream>>>(ca, x_f, flag, acc);

  prep_kernel<<<1152, 256, 0, stream>>>(wqkv_f, wout_f, wm1_f, wm2_f, temp_f,
                                        wqkv_b, wout_b, wm1_b, wm2_b, qscale);

  gn_t_kernel<<<64, 256, 0, stream>>>(x_f, g1_f, be1_f, xn_t);

  mfma_gemm<256, 4, 0, 0, 768><<<dim3(512, 3), 256, 0, stream>>>(
      wqkv_b, xn_t, qscale, nullptr, nullptr, qkv_t, flag);

  vrepack_kernel<<<dim3(128, 4), 256, 0, stream>>>(qkv_t, vs);

  attn2_kernel<<<dim3(64, NHEAD, NB), 256, 0, stream>>>(qkv_t, vs, aout_t);

  mfma_gemm<256, 4, 1, 0, 0><<<dim3(512, 1), 256, 0, stream>>>(
      wout_b, aout_t, nullptr, bout_f, x_f, xres, flag);

  gn_t_kernel<<<64, 256, 0, stream>>>(xres, g2_f, be2_f, ybuf_t);

  mfma_gemm<256, 1, 0, 1, 64><<<dim3(512, 1), 256, 0, stream>>>(
      wm1_b, ybuf_t, nullptr, bm1_f, nullptr, h_t, flag);

  mfma_gemm<64, 4, 2, 0, 0><<<dim3(512, 1), 256, 0, stream>>>(
      wm2_b, h_t, nullptr, bm2_f, xres, d_out, flag);
}

// Round 6
// 366.614 us; speedup vs baseline: 1.4237x; 1.4237x over previous
//
#include <hip/hip_runtime.h>
#include <hip/hip_bf16.h>
#include <math.h>

// Problem constants (B=2, C=256, H=W=64, heads=8, hd=32, groups=32, hid=64)
#define NB 2
#define NC 256
#define NHEAD 8
#define HD 32
#define NPIX 4096
#define GEPS 1e-5f

typedef short bf16x8 __attribute__((ext_vector_type(8)));
typedef float f32x4 __attribute__((ext_vector_type(4)));

union U16x8 { uint4 u4; uint2 u2[2]; unsigned u32[4]; unsigned short us[8]; bf16x8 v; };

__device__ inline unsigned short tobf(float f) {  // round-to-nearest-even
  union { float f; unsigned u; } c; c.f = f;
  return (unsigned short)((c.u + 0x7FFFu + ((c.u >> 16) & 1u)) >> 16);
}
__device__ inline unsigned packtrunc(float lo, float hi) {  // truncating bf16 pack
  return (__float_as_uint(lo) >> 16) | (__float_as_uint(hi) & 0xFFFF0000u);
}

// ---------------------------------------------------------------------------
// Dtype detection (bf16 vs fp32 inputs).
// ---------------------------------------------------------------------------
__global__ void detect_kernel(const void* __restrict__ x, int* __restrict__ flag) {
  int lane = threadIdx.x;
  const unsigned short* u = (const unsigned short*)x;
  unsigned short h = u[2 * lane];
  unsigned e = (h >> 7) & 0xFFu;
  int weird = (e < 113u || e > 140u) ? 1 : 0;
  unsigned long long mask = __ballot(weird);
  if (lane == 0) flag[0] = (__popcll(mask) > 16) ? 0 : 1;
}

struct ConvArgs { const void* src[13]; int off[14]; };

__global__ __launch_bounds__(256) void convert_all_kernel(ConvArgs a, float* __restrict__ dstbase,
                                                          const int* __restrict__ flag, int total) {
  int i = blockIdx.x * 256 + threadIdx.x;
  if (i >= total) return;
  int s = 0;
  while (i >= a.off[s + 1]) ++s;
  int local = i - a.off[s];
  if (*flag) {
    unsigned v = ((const unsigned short*)a.src[s])[local];
    dstbase[i] = __uint_as_float(v << 16);
  } else {
    dstbase[i] = ((const float*)a.src[s])[local];
  }
}

// ---------------------------------------------------------------------------
// Prep: weights fp32->bf16 + qscale (temp*log2e for o<256 else 1).
// ---------------------------------------------------------------------------
__global__ __launch_bounds__(256) void prep_kernel(
    const float* __restrict__ wqkv, const float* __restrict__ wout,
    const float* __restrict__ wm1, const float* __restrict__ wm2,
    const float* __restrict__ temp,
    unsigned short* __restrict__ wqkv_b, unsigned short* __restrict__ wout_b,
    unsigned short* __restrict__ wm1_b, unsigned short* __restrict__ wm2_b,
    float* __restrict__ qscale) {
  int i = blockIdx.x * 256 + threadIdx.x;
  if (i < 196608) wqkv_b[i] = tobf(wqkv[i]);
  else if (i < 262144) wout_b[i - 196608] = tobf(wout[i - 196608]);
  else if (i < 278528) wm1_b[i - 262144] = tobf(wm1[i - 262144]);
  else if (i < 294912) wm2_b[i - 278528] = tobf(wm2[i - 278528]);
  if (i < 768) {
    if (i < 256) {
      float tc = fminf(fmaxf(temp[i >> 5], 1e-4f), 10.f);
      qscale[i] = tc * 1.4426950408889634f;
    } else qscale[i] = 1.0f;
  }
}

// ---------------------------------------------------------------------------
// GroupNorm stats, NO atomics: 256 blocks, each reduces one quarter of a
// (b,group) slab and stores a deterministic partial pair part[blk*2 + {0,1}].
// ---------------------------------------------------------------------------
__global__ __launch_bounds__(256) void gn_stats_kernel(const float* __restrict__ in,
                                                       float* __restrict__ part) {
  int blk = blockIdx.x;          // 256 blocks: bg = blk>>2, quarter = blk&3
  int bg = blk >> 2, q = blk & 3;
  const float* base = in + (size_t)bg * 32768 + q * 8192;
  int t = threadIdx.x;
  float s = 0.f, s2 = 0.f;
  for (int i = t; i < 8192; i += 256) { float v = base[i]; s += v; s2 += v * v; }
  __shared__ float rs[256], rq[256];
  rs[t] = s; rq[t] = s2;
  __syncthreads();
  for (int o = 128; o > 0; o >>= 1) {
    if (t < o) { rs[t] += rs[t + o]; rq[t] += rq[t + o]; }
    __syncthreads();
  }
  if (t == 0) { part[blk * 2] = rs[0]; part[blk * 2 + 1] = rq[0]; }
}

// ---------------------------------------------------------------------------
// GroupNorm apply + transpose to bf16 pixel-major [p][256]. 512 blocks.
// Reduces the 4 partials per group inline (deterministic).
// ---------------------------------------------------------------------------
__global__ __launch_bounds__(256) void gn_apply_kernel(
    const float* __restrict__ in, const float* __restrict__ part,
    const float* __restrict__ gamma, const float* __restrict__ beta,
    unsigned short* __restrict__ outt) {
  int t = threadIdx.x;
  int p = blockIdx.x * 16 + (t & 15);
  int cg = t >> 4;
  int b = p >> 12, n = p & 4095;
  const float* src = in + ((size_t)b * NC + cg * 16) * NPIX + n;
  U16x8 lo, hi;
#pragma unroll
  for (int cc = 0; cc < 16; ++cc) {
    int c = cg * 16 + cc;
    int bg = b * 32 + (c >> 3);
    const float* pp = &part[bg * 8];   // [q][2] partials, q<4
    float s  = (pp[0] + pp[2]) + (pp[4] + pp[6]);
    float s2 = (pp[1] + pp[3]) + (pp[5] + pp[7]);
    float mean = s * (1.f / 32768.f);
    float inv = rsqrtf(s2 * (1.f / 32768.f) - mean * mean + GEPS);
    float gg = gamma[c] * inv;
    float vv = (src[(size_t)cc * NPIX] - mean) * gg + beta[c];
    if (cc < 8) lo.us[cc] = tobf(vv); else hi.us[cc - 8] = tobf(vv);
  }
  unsigned short* dst = outt + (size_t)p * NC + cg * 16;
  *(uint4*)dst = lo.u4;
  *(uint4*)(dst + 8) = hi.u4;
}

// ---------------------------------------------------------------------------
// bf16 MFMA GEMM, LDS-free. W [M][K] row-major (A), X [p][K] pixel-major (B).
// EPI 0: bf16 pixel-major out (OSTR stride), optional scale/bias/GELU
// EPI 1: fp32 channel-major out + bias + residual
// EPI 2: final out (flag dtype) + bias + residual, channel-major
// EPI 3: QKV split: Q->out [bh][n][32] (pre-scaled), K->out2 [bh][n][32],
//        V->out3 [b][c][n] channel-major
// ---------------------------------------------------------------------------
template <int K, int OT, int EPI, int ACT, int OSTR>
__global__ __launch_bounds__(256) void mfma_gemm(
    const unsigned short* __restrict__ W, const unsigned short* __restrict__ X,
    const float* __restrict__ scale, const float* __restrict__ bias,
    const float* __restrict__ res, void* __restrict__ out,
    void* __restrict__ out2, void* __restrict__ out3,
    const int* __restrict__ flag) {
  int t = threadIdx.x;
  int w = t >> 6, lane = t & 63, l16 = lane & 15, quad = lane >> 4;
  int p = blockIdx.x * 16 + l16;
  int ob = blockIdx.y * (64 * OT) + w * (16 * OT);
  const unsigned short* xrow = X + (size_t)p * K + quad * 8;
  f32x4 acc[OT] = {};
#pragma unroll
  for (int k0 = 0; k0 < K; k0 += 32) {
    U16x8 bfr; bfr.u4 = *(const uint4*)(xrow + k0);
#pragma unroll
    for (int ot = 0; ot < OT; ++ot) {
      U16x8 af;
      af.u4 = *(const uint4*)(W + (size_t)(ob + ot * 16 + l16) * K + k0 + quad * 8);
      acc[ot] = __builtin_amdgcn_mfma_f32_16x16x32_bf16(af.v, bfr.v, acc[ot], 0, 0, 0);
    }
  }
  int b = p >> 12, n = p & 4095;
  int wbf = (EPI == 2) ? *flag : 0;
#pragma unroll
  for (int ot = 0; ot < OT; ++ot) {
    int oc = ob + ot * 16 + quad * 4;
    float v[4];
#pragma unroll
    for (int r = 0; r < 4; ++r) {
      float vv = acc[ot][r];
      if (scale) vv *= scale[oc + r];
      if (bias) vv += bias[oc + r];
      if (ACT == 1) vv = 0.5f * vv * (1.f + erff(vv * 0.70710678118654752f));
      v[r] = vv;
    }
    if (EPI == 0) {
      uint2 pk;
      pk.x = (unsigned)tobf(v[0]) | ((unsigned)tobf(v[1]) << 16);
      pk.y = (unsigned)tobf(v[2]) | ((unsigned)tobf(v[3]) << 16);
      *(uint2*)((unsigned short*)out + (size_t)p * OSTR + oc) = pk;
    } else if (EPI == 3) {
      int sec = oc >> 8;  // block-uniform: 0=Q, 1=K, 2=V
      int c = oc & 255;
      if (sec < 2) {
        int hh = c >> 5, d = c & 31;
        unsigned short* base = (unsigned short*)(sec == 0 ? out : out2);
        uint2 pk;
        pk.x = (unsigned)tobf(v[0]) | ((unsigned)tobf(v[1]) << 16);
        pk.y = (unsigned)tobf(v[2]) | ((unsigned)tobf(v[3]) << 16);
        *(uint2*)(base + ((size_t)(b * NHEAD + hh) * NPIX + n) * HD + d) = pk;
      } else {
        unsigned short* vsb = (unsigned short*)out3;
#pragma unroll
        for (int r = 0; r < 4; ++r)
          vsb[((size_t)(b * NC + c + r)) * NPIX + n] = tobf(v[r]);
      }
    } else {
#pragma unroll
      for (int r = 0; r < 4; ++r) {
        size_t oidx = ((size_t)(b * NC + oc + r)) * NPIX + n;
        float vv = v[r] + res[oidx];
        if (EPI == 2) {
          if (wbf) ((__hip_bfloat16*)out)[oidx] = __float2bfloat16(vv);
          else ((float*)out)[oidx] = vv;
        } else {
          ((float*)out)[oidx] = vv;
        }
      }
    }
  }
}

// ---------------------------------------------------------------------------
// MFMA flash attention v4: round-2/4 proven static structure (single-tile
// prefetch, compile-time indices only, Pl pad 72 = 16B-aligned rows), on
// coalesced layouts: qn/kn [bh][n][32] (Q pre-scaled by temp*log2e),
// vs [b][c][n]. P = exp2(S^T) trunc-bf16; l via ones-MFMA; O^T = V P^T.
// ---------------------------------------------------------------------------
__global__ __launch_bounds__(256) void attn4_kernel(
    const unsigned short* __restrict__ qn, const unsigned short* __restrict__ kn,
    const unsigned short* __restrict__ vs, unsigned short* __restrict__ aout_t) {
  int i0 = blockIdx.x * 64;
  int h = blockIdx.y, b = blockIdx.z;
  int bh = b * NHEAD + h;
  int t = threadIdx.x;
  int w = t >> 6, lane = t & 63, l16 = lane & 15, quad = lane >> 4;

  __shared__ unsigned short Pl[4][16][72];

  U16x8 qf;
  qf.u4 = *(const uint4*)(qn + ((size_t)bh * NPIX + i0 + w * 16 + l16) * HD + quad * 8);
  U16x8 ones;
#pragma unroll
  for (int j = 0; j < 8; ++j) ones.us[j] = 0x3F80;

  const unsigned short* kbase = kn + (size_t)bh * NPIX * HD + quad * 8;
  const unsigned short* vrow0 = vs + ((size_t)(b * NC + h * HD + l16)) * NPIX + quad * 8;
  const unsigned short* vrow1 = vrow0 + (size_t)16 * NPIX;

  f32x4 o0 = {0.f, 0.f, 0.f, 0.f}, o1 = {0.f, 0.f, 0.f, 0.f};
  f32x4 lacc = {0.f, 0.f, 0.f, 0.f};
  const f32x4 zf = {0.f, 0.f, 0.f, 0.f};

  U16x8 kf[4], vf0[2], vf1[2];
#pragma unroll
  for (int jt = 0; jt < 4; ++jt)
    kf[jt].u4 = *(const uint4*)(kbase + (size_t)(jt * 16 + l16) * HD);
#pragma unroll
  for (int ks = 0; ks < 2; ++ks) {
    vf0[ks].u4 = *(const uint4*)(vrow0 + ks * 32);
    vf1[ks].u4 = *(const uint4*)(vrow1 + ks * 32);
  }

  for (int j0 = 0; j0 < NPIX; j0 += 64) {
    int jn = (j0 + 64) & (NPIX - 1);  // wraps on last iter; harmless prefetch
    U16x8 kp[4], v0p[2], v1p[2];
#pragma unroll
    for (int jt = 0; jt < 4; ++jt)
      kp[jt].u4 = *(const uint4*)(kbase + (size_t)(jn + jt * 16 + l16) * HD);
#pragma unroll
    for (int ks = 0; ks < 2; ++ks) {
      v0p[ks].u4 = *(const uint4*)(vrow0 + jn + ks * 32);
      v1p[ks].u4 = *(const uint4*)(vrow1 + jn + ks * 32);
    }
    f32x4 st[4];
#pragma unroll
    for (int jt = 0; jt < 4; ++jt)
      st[jt] = __builtin_amdgcn_mfma_f32_16x16x32_bf16(kf[jt].v, qf.v, zf, 0, 0, 0);
#pragma unroll
    for (int jt = 0; jt < 4; ++jt) {
      uint2 pk;
      pk.x = packtrunc(__builtin_amdgcn_exp2f(st[jt][0]), __builtin_amdgcn_exp2f(st[jt][1]));
      pk.y = packtrunc(__builtin_amdgcn_exp2f(st[jt][2]), __builtin_amdgcn_exp2f(st[jt][3]));
      *(uint2*)&Pl[w][l16][jt * 16 + quad * 4] = pk;
    }
#pragma unroll
    for (int ks = 0; ks < 2; ++ks) {
      U16x8 pb; pb.u4 = *(const uint4*)&Pl[w][l16][ks * 32 + quad * 8];
      o0 = __builtin_amdgcn_mfma_f32_16x16x32_bf16(vf0[ks].v, pb.v, o0, 0, 0, 0);
      o1 = __builtin_amdgcn_mfma_f32_16x16x32_bf16(vf1[ks].v, pb.v, o1, 0, 0, 0);
      lacc = __builtin_amdgcn_mfma_f32_16x16x32_bf16(ones.v, pb.v, lacc, 0, 0, 0);
    }
#pragma unroll
    for (int jt = 0; jt < 4; ++jt) kf[jt] = kp[jt];
#pragma unroll
    for (int ks = 0; ks < 2; ++ks) { vf0[ks] = v0p[ks]; vf1[ks] = v1p[ks]; }
  }

  float rinv = 1.0f / lacc[0];  // all 4 regs hold l[col=l16]
  uint2 s0, s1;
  s0.x = (unsigned)tobf(o0[0] * rinv) | ((unsigned)tobf(o0[1] * rinv) << 16);
  s0.y = (unsigned)tobf(o0[2] * rinv) | ((unsigned)tobf(o0[3] * rinv) << 16);
  s1.x = (unsigned)tobf(o1[0] * rinv) | ((unsigned)tobf(o1[1] * rinv) << 16);
  s1.y = (unsigned)tobf(o1[2] * rinv) | ((unsigned)tobf(o1[3] * rinv) << 16);
  unsigned short* obp = aout_t + ((size_t)b * NPIX + i0 + w * 16 + l16) * NC + h * 32 + quad * 4;
  *(uint2*)obp = s0;
  *(uint2*)(obp + 16) = s1;
}

// ---------------------------------------------------------------------------
// Launch pipeline. (off is in FLOAT units; bf16 buffers advance by N/2.)
// ---------------------------------------------------------------------------
extern "C" void kernel_launch(void* const* d_in, const int* in_sizes, int n_in,
                              void* d_out, int out_size, void* d_ws, size_t ws_size,
                              hipStream_t stream) {
  float* ws = (float*)d_ws;
  int* flag = (int*)d_ws;
  size_t off = 16;
  float* x_f    = ws + off; off += (size_t)NB * NC * NPIX;
  float* wqkv_f = ws + off; off += 768 * 256;
  float* wout_f = ws + off; off += 256 * 256;
  float* bout_f = ws + off; off += 256;
  float* temp_f = ws + off; off += 8;
  float* g1_f   = ws + off; off += 256;
  float* be1_f  = ws + off; off += 256;
  float* g2_f   = ws + off; off += 256;
  float* be2_f  = ws + off; off += 256;
  float* wm1_f  = ws + off; off += 64 * 256;
  float* bm1_f  = ws + off; off += 64;
  float* wm2_f  = ws + off; off += 256 * 64;
  float* bm2_f  = ws + off; off += 256;
  float* xres   = ws + off; off += (size_t)NB * NC * NPIX;
  unsigned short* xn_t   = (unsigned short*)(ws + off); off += 1048576;  // [8192][256]
  unsigned short* qn     = (unsigned short*)(ws + off); off += 1048576;  // [16][4096][32]
  unsigned short* kn     = (unsigned short*)(ws + off); off += 1048576;  // [16][4096][32]
  unsigned short* vs     = (unsigned short*)(ws + off); off += 1048576;  // [2][256][4096]
  unsigned short* aout_t = (unsigned short*)(ws + off); off += 1048576;  // [8192][256]
  unsigned short* ybuf_t = (unsigned short*)(ws + off); off += 1048576;  // [8192][256]
  unsigned short* h_t    = (unsigned short*)(ws + off); off += 262144;   // [8192][64]
  unsigned short* wqkv_b = (unsigned short*)(ws + off); off += 98304;
  unsigned short* wout_b = (unsigned short*)(ws + off); off += 32768;
  unsigned short* wm1_b  = (unsigned short*)(ws + off); off += 8192;
  unsigned short* wm2_b  = (unsigned short*)(ws + off); off += 8192;
  float* qscale = ws + off; off += 768;
  float* part1  = ws + off; off += 512;   // GN1 partials [256][2]
  float* part2  = ws + off; off += 512;   // GN2 partials

  detect_kernel<<<1, 64, 0, stream>>>(d_in[0], flag);

  ConvArgs ca;
  int acc = 0;
  for (int i = 0; i < 13; ++i) {
    ca.src[i] = d_in[i];
    ca.off[i] = acc;
    acc += (i < n_in) ? in_sizes[i] : 0;
  }
  ca.off[13] = acc;
  convert_all_kernel<<<(acc + 255) / 256, 256, 0, stream>>>(ca, x_f, flag, acc);

  prep_kernel<<<1152, 256, 0, stream>>>(wqkv_f, wout_f, wm1_f, wm2_f, temp_f,
                                        wqkv_b, wout_b, wm1_b, wm2_b, qscale);

  gn_stats_kernel<<<256, 256, 0, stream>>>(x_f, part1);
  gn_apply_kernel<<<512, 256, 0, stream>>>(x_f, part1, g1_f, be1_f, xn_t);

  mfma_gemm<256, 4, 3, 0, 0><<<dim3(512, 3), 256, 0, stream>>>(
      wqkv_b, xn_t, qscale, nullptr, nullptr, qn, kn, vs, flag);

  attn4_kernel<<<dim3(64, NHEAD, NB), 256, 0, stream>>>(qn, kn, vs, aout_t);

  mfma_gemm<256, 4, 1, 0, 0><<<dim3(512, 1), 256, 0, stream>>>(
      wout_b, aout_t, nullptr, bout_f, x_f, xres, nullptr, nullptr, flag);

  gn_stats_kernel<<<256, 256, 0, stream>>>(xres, part2);
  gn_apply_kernel<<<512, 256, 0, stream>>>(xres, part2, g2_f, be2_f, ybuf_t);

  mfma_gemm<256, 1, 0, 1, 64><<<dim3(512, 1), 256, 0, stream>>>(
      wm1_b, ybuf_t, nullptr, bm1_f, nullptr, h_t, nullptr, nullptr, flag);

  mfma_gemm<64, 4, 2, 0, 0><<<dim3(512, 1), 256, 0, stream>>>(
      wm2_b, h_t, nullptr, bm2_f, xres, d_out, nullptr, nullptr, flag);
}